// Round 9
// baseline (1740.939 us; speedup 1.0000x reference)
//
#include <hip/hip_runtime.h>

#define T4096 4096
#define CH 64
typedef unsigned long long u64;

// ---------------------------------------------------------------------------
// QKV: O[b][s][c] = sum_t W[s][t] * X[b][c][t]   (NT gemm, both row-major in t)
// tile 128(s) x 64(c), K-step 32 (25.6 KB LDS -> 6 blocks/CU). 256 thr,
// 8x4 micro-tile. LDS [k][col^swz], swizzle col = row ^ (k & 28) (0 conflicts).
// Q stored TILED: Qr2[b][blk=s/64][c4g][sl=s%64][4].
// Per-output fmaf chain k-ascending -> bit-identical to all prior rounds.
// ---------------------------------------------------------------------------
__global__ __launch_bounds__(256) void gemm_qkv(
    const float* __restrict__ X,
    const float* __restrict__ Wq, const float* __restrict__ Wk, const float* __restrict__ Wv,
    float* __restrict__ QT, float* __restrict__ KT, float* __restrict__ VT)
{
    const float* W = (blockIdx.z == 0) ? Wq : (blockIdx.z == 1) ? Wk : Wv;
    float*       O = (blockIdx.z == 0) ? QT : (blockIdx.z == 1) ? KT : VT;
    const int b  = blockIdx.y;
    const int s0 = blockIdx.x * 128;

    __shared__ float As[32][132];   // [k][m^swz]
    __shared__ float Bs[32][68];    // [k][c^swz]

    const int tid = threadIdx.x;
    const int tx = tid & 15;   const int c0 = tx * 4;
    const int my = tid >> 4;   const int m0 = my * 8;
    const int lr = tid >> 3;            // 0..31
    const int lk = (tid & 7) * 4;       // 0..28
    const int sw = lk;

    float acc[8][4];
#pragma unroll
    for (int i = 0; i < 8; ++i)
#pragma unroll
        for (int j = 0; j < 4; ++j) acc[i][j] = 0.f;

    const float* Xb = X + (size_t)b * CH * T4096;

    for (int k0 = 0; k0 < T4096; k0 += 32) {
#pragma unroll
        for (int p = 0; p < 4; ++p) {   // A: 128 rows
            int row = lr + 32 * p;
            float4 v = *(const float4*)(W + (size_t)(s0 + row) * T4096 + k0 + lk);
            int col = row ^ sw;
            As[lk + 0][col] = v.x; As[lk + 1][col] = v.y;
            As[lk + 2][col] = v.z; As[lk + 3][col] = v.w;
        }
#pragma unroll
        for (int p = 0; p < 2; ++p) {   // B: 64 rows (channels)
            int row = lr + 32 * p;
            float4 v = *(const float4*)(Xb + (size_t)row * T4096 + k0 + lk);
            int col = row ^ sw;
            Bs[lk + 0][col] = v.x; Bs[lk + 1][col] = v.y;
            Bs[lk + 2][col] = v.z; Bs[lk + 3][col] = v.w;
        }
        __syncthreads();
#pragma unroll
        for (int k = 0; k < 32; ++k) {
            const int swk = k & 28;
            float4 a0 = *(const float4*)&As[k][(m0) ^ swk];
            float4 a1 = *(const float4*)&As[k][(m0 + 4) ^ swk];
            float4 bv = *(const float4*)&Bs[k][c0 ^ swk];
            float am[8] = {a0.x,a0.y,a0.z,a0.w,a1.x,a1.y,a1.z,a1.w};
            float bn[4] = {bv.x,bv.y,bv.z,bv.w};
#pragma unroll
            for (int i = 0; i < 8; ++i)
#pragma unroll
                for (int j = 0; j < 4; ++j) acc[i][j] = fmaf(am[i], bn[j], acc[i][j]);
        }
        __syncthreads();
    }
    if (blockIdx.z == 0) {
        // tiled store: Qr2[b][blk][c4g=tx][sl][4]
#pragma unroll
        for (int i = 0; i < 8; ++i) {
            int s = s0 + m0 + i;
            *(float4*)(O + ((((size_t)b * 64 + (s >> 6)) * 16 + tx) * 64 + (s & 63)) * 4) =
                make_float4(acc[i][0], acc[i][1], acc[i][2], acc[i][3]);
        }
    } else {
#pragma unroll
        for (int i = 0; i < 8; ++i) {
            *(float4*)(O + ((size_t)b * T4096 + s0 + m0 + i) * CH + c0) =
                make_float4(acc[i][0], acc[i][1], acc[i][2], acc[i][3]);
        }
    }
}

// ---------------------------------------------------------------------------
// In-place L2 normalize over the 64 channels of each token (Q then K).
// One wave per token. Q uses the tiled layout; lane<->channel mapping and
// the butterfly order are unchanged -> bit-exact.
// ---------------------------------------------------------------------------
__global__ __launch_bounds__(256) void normalize_qk(float* __restrict__ QT, float* __restrict__ KT)
{
    int gtok = blockIdx.x * 4 + (threadIdx.x >> 6);
    int lane = threadIdx.x & 63;
    bool isQ = (gtok < 8 * T4096);
    int t = gtok & (T4096 - 1);
    int b = (gtok >> 12) & 7;
    float* p;
    if (isQ) p = QT + ((((size_t)b * 64 + (t >> 6)) * 16 + (lane >> 2)) * 64 + (t & 63)) * 4 + (lane & 3);
    else     p = KT + ((size_t)b * T4096 + t) * CH + lane;
    float v = *p;
    float ss = v * v;
#pragma unroll
    for (int off = 32; off; off >>= 1) ss += __shfl_xor(ss, off);
    float n = fmaxf(sqrtf(ss), 1e-12f);
    *p = v / n;
}

// ---------------------------------------------------------------------------
// Fused sim + top-9, v8: 2 rows x 8 cols per thread (256-col chunks, 16
// iters). K-fragment LDS reads per candidate drop 4x vs v6/v7; 16 indep
// fma chains. 1024 blocks x 512 thr (4 blocks/CU); b = wg & 7 (XCD affinity).
// thread(tx=tid&31, ty=tid>>5 in 0..15): rows {ty, 16+ty},
// cols it*256 + 32*cc + tx (cc 0..7).
// u64 key = (bits(v)<<32)|(4095-s); 32-bit pre-guard on the value bits
// (vb >= thr_hi, necessary condition for key > thr) keeps the common
// reject path at ~2 ops. thr = max over 32 lanes of lane-9th (safe lower
// bound on row 9th; keys unique -> exact). Selection semantics identical
// to v5-v7 -> IDX bit-identical. fmaf chain per (t,s): c4g asc, xyzw.
// #pragma unroll 1 on c4g: cap in-flight loads (R6 spill lesson).
// ---------------------------------------------------------------------------
__global__ __launch_bounds__(512) void sim_topk(
    const float* __restrict__ Qr, const float* __restrict__ KT, int* __restrict__ IDX)
{
    const int wg = blockIdx.x;
    const int b  = wg & 7;              // XCD affinity
    const int t0 = (wg >> 3) * 32;

    __shared__ float Kn[32][68];

    const int tid = threadIdx.x;
    const int tx = tid & 31;
    const int ty = tid >> 5;            // 0..15

    {   // stage 32 rows x 64 floats, 4 floats/thread (one-time)
        int row = tid >> 4; int cc = (tid & 15) * 4;
        *(float4*)&Kn[row][cc] =
            *(const float4*)(KT + ((size_t)b * T4096 + t0 + row) * CH + cc);
    }
    __syncthreads();

    u64 tv[2][9];
#pragma unroll
    for (int r = 0; r < 2; ++r)
#pragma unroll
        for (int q = 0; q < 9; ++q) tv[r][q] = 0ULL;
    u64 thr[2] = {0ULL, 0ULL};
    unsigned thr_hi[2] = {0u, 0u};

    const float* qb0 = Qr + ((size_t)b * 64 * 1024 + tx) * 4;

    for (int it = 0; it < 16; ++it) {
        // chunk = 256 cols = 4 Q-tiles (blk = it*4 .. it*4+3), each 4096 floats
        const float* bp = qb0 + (size_t)(it * 4) * 4096;
        float acc[2][8];
#pragma unroll
        for (int c = 0; c < 8; ++c) { acc[0][c] = 0.f; acc[1][c] = 0.f; }

#pragma unroll 1
        for (int c4g = 0; c4g < 16; ++c4g) {
            float4 qv[8];
#pragma unroll
            for (int cc = 0; cc < 8; ++cc)
                qv[cc] = *(const float4*)(bp + (size_t)(cc >> 1) * 4096
                                             + c4g * 256 + (cc & 1) * 128);
            float4 k0 = *(const float4*)&Kn[ty][c4g * 4];
            float4 k1 = *(const float4*)&Kn[16 + ty][c4g * 4];
#pragma unroll
            for (int cc = 0; cc < 8; ++cc) {
                acc[0][cc] = fmaf(k0.x, qv[cc].x, acc[0][cc]);
                acc[0][cc] = fmaf(k0.y, qv[cc].y, acc[0][cc]);
                acc[0][cc] = fmaf(k0.z, qv[cc].z, acc[0][cc]);
                acc[0][cc] = fmaf(k0.w, qv[cc].w, acc[0][cc]);
                acc[1][cc] = fmaf(k1.x, qv[cc].x, acc[1][cc]);
                acc[1][cc] = fmaf(k1.y, qv[cc].y, acc[1][cc]);
                acc[1][cc] = fmaf(k1.z, qv[cc].z, acc[1][cc]);
                acc[1][cc] = fmaf(k1.w, qv[cc].w, acc[1][cc]);
            }
        }

        bool ins = false;
        const int sb = it * 256 + tx;
#pragma unroll
        for (int rr = 0; rr < 2; ++rr)
#pragma unroll
            for (int cc = 0; cc < 8; ++cc) {
                float v = fmaxf(acc[rr][cc], 0.f);     // clip BEFORE top-k (as ref)
                unsigned vb = __float_as_uint(v);
                if (vb >= thr_hi[rr]) {                // cheap 32-bit pre-guard
                    int s = sb + 32 * cc;
                    u64 key = ((u64)vb << 32) | (u64)(4095 - s);
                    if (key > thr[rr]) {               // exact guard
                        u64 cv = key;
#pragma unroll
                        for (int p = 0; p < 9; ++p) {  // branchless sorted insert
                            u64 t  = tv[rr][p];
                            bool g = cv > t;
                            tv[rr][p] = g ? cv : t;
                            cv        = g ? t  : cv;
                        }
                        ins = true;
                    }
                }
            }
        if (__any(ins)) {   // refresh row lower bounds (max of lane 9ths)
#pragma unroll
            for (int r = 0; r < 2; ++r) {
                u64 m = tv[r][8];
#pragma unroll
                for (int msk = 1; msk < 32; msk <<= 1) {
                    u64 o = __shfl_xor(m, msk);
                    if (o > m) m = o;
                }
                thr[r] = m;
                thr_hi[r] = (unsigned)(m >> 32);
            }
        }
    }

    // in-wave merge: 32 lanes sharing ty hold sorted 9-lists for row rr*16+ty.
    // 9 selection rounds of 32-lane xor-reduce on u64 keys.
#pragma unroll
    for (int rr = 0; rr < 2; ++rr) {
        u64 mv[9];
#pragma unroll
        for (int q = 0; q < 9; ++q) mv[q] = tv[rr][q];
        const int outrow = t0 + rr * 16 + ty;
        int* dst = IDX + ((size_t)b * T4096 + outrow) * 9;
        for (int sel = 0; sel < 9; ++sel) {
            u64 bk = mv[0]; int bl = tx;
#pragma unroll
            for (int m = 1; m < 32; m <<= 1) {
                u64 ok = __shfl_xor(bk, m);
                int ol = __shfl_xor(bl, m);
                if (ok > bk) { bk = ok; bl = ol; }
            }
            if (tx == 0) dst[sel] = 4095 - (int)(unsigned)bk;
            if (tx == bl) {   // consume winner: static shift
#pragma unroll
                for (int q = 0; q < 8; ++q) mv[q] = mv[q + 1];
                mv[8] = 0ULL;
            }
        }
    }
}

// ---------------------------------------------------------------------------
// conv_w [o][i][j] -> wT3 [j][i/4][o][4] for coalesced float4 lane loads
// ---------------------------------------------------------------------------
__global__ void transpose_w(const float* __restrict__ cw, float* __restrict__ wT3)
{
    int idx = blockIdx.x * 256 + threadIdx.x;
    if (idx >= 64 * 64 * 9) return;
    int q   = idx & 3;
    int o   = (idx >> 2) & 63;
    int i4g = (idx >> 8) & 15;
    int j   = idx >> 12;
    wT3[idx] = cw[o * 576 + (i4g * 4 + q) * 9 + j];
}

// ---------------------------------------------------------------------------
// gather + conv1d(K=9, stride 9) + bias. Wave = 4 tokens x 64 o-lanes.
// out1 layout [b][t][o] (coalesced write, transpose-free LDS load in gemm_out)
// ---------------------------------------------------------------------------
__global__ __launch_bounds__(256) void gather_conv(
    const float* __restrict__ VT, const int* __restrict__ IDX,
    const float* __restrict__ wT3, const float* __restrict__ conv_b,
    float* __restrict__ out1)
{
    const int b  = blockIdx.y;
    const int w  = threadIdx.x >> 6;
    const int o  = threadIdx.x & 63;
    const int t0 = (blockIdx.x * 4 + w) * 4;

    __shared__ float vv[4][4][9][64];
    __shared__ int   nb[4][36];

    if (o < 36) nb[w][o] = IDX[((size_t)b * T4096 + t0) * 9 + o];
    __syncthreads();

#pragma unroll
    for (int tok = 0; tok < 4; ++tok)
#pragma unroll
        for (int j = 0; j < 9; ++j) {
            int n = nb[w][tok * 9 + j];
            vv[w][tok][j][o] = VT[((size_t)b * T4096 + n) * CH + o];
        }
    __syncthreads();

    float cb = conv_b[o];
    float a0 = cb, a1 = cb, a2 = cb, a3 = cb;
    for (int j = 0; j < 9; ++j) {
#pragma unroll
        for (int i4 = 0; i4 < 16; ++i4) {
            float4 w4 = *(const float4*)(wT3 + (((size_t)j * 16 + i4) * 64 + o) * 4);
            float4 v0 = *(const float4*)&vv[w][0][j][i4 * 4];
            float4 v1 = *(const float4*)&vv[w][1][j][i4 * 4];
            float4 v2 = *(const float4*)&vv[w][2][j][i4 * 4];
            float4 v3 = *(const float4*)&vv[w][3][j][i4 * 4];
            a0 = fmaf(v0.x, w4.x, a0); a0 = fmaf(v0.y, w4.y, a0); a0 = fmaf(v0.z, w4.z, a0); a0 = fmaf(v0.w, w4.w, a0);
            a1 = fmaf(v1.x, w4.x, a1); a1 = fmaf(v1.y, w4.y, a1); a1 = fmaf(v1.z, w4.z, a1); a1 = fmaf(v1.w, w4.w, a1);
            a2 = fmaf(v2.x, w4.x, a2); a2 = fmaf(v2.y, w4.y, a2); a2 = fmaf(v2.z, w4.z, a2); a2 = fmaf(v2.w, w4.w, a2);
            a3 = fmaf(v3.x, w4.x, a3); a3 = fmaf(v3.y, w4.y, a3); a3 = fmaf(v3.z, w4.z, a3); a3 = fmaf(v3.w, w4.w, a3);
        }
    }
    out1[((size_t)b * T4096 + t0 + 0) * CH + o] = a0;
    out1[((size_t)b * T4096 + t0 + 1) * CH + o] = a1;
    out1[((size_t)b * T4096 + t0 + 2) * CH + o] = a2;
    out1[((size_t)b * T4096 + t0 + 3) * CH + o] = a3;
}

// ---------------------------------------------------------------------------
// Final: Out[b][c][s] = sum_t out1[b][t][c] * Wo[s][t]
// tile 64(c) x 128(s), K-step 32. 4x8 micro-tile, s-contiguous writes.
// ---------------------------------------------------------------------------
__global__ __launch_bounds__(256) void gemm_out(
    const float* __restrict__ out1, const float* __restrict__ Wo, float* __restrict__ Out)
{
    const int b  = blockIdx.y;
    const int s0 = blockIdx.x * 128;
    __shared__ float As[32][68];    // [k][c]
    __shared__ float Bs[32][132];   // [k][s^swz]
    const int tid = threadIdx.x;
    const int tx = tid & 15;  const int sl = tx * 8;
    const int my = tid >> 4;  const int c0 = my * 4;
    const int lr = tid >> 3;
    const int lk = (tid & 7) * 4;
    const int sw = lk;

    float acc[4][8];
#pragma unroll
    for (int i = 0; i < 4; ++i)
#pragma unroll
        for (int j = 0; j < 8; ++j) acc[i][j] = 0.f;

    for (int k0 = 0; k0 < T4096; k0 += 32) {
        {   // A: out1 is [t][c] -> direct [k][c] copy, no transpose
            int r  = tid >> 3;
            int cL = (tid & 7) * 8;
            const float* src = out1 + ((size_t)b * T4096 + k0 + r) * CH + cL;
            *(float4*)&As[r][cL]     = *(const float4*)(src);
            *(float4*)&As[r][cL + 4] = *(const float4*)(src + 4);
        }
#pragma unroll
        for (int p = 0; p < 4; ++p) {   // B: Wo rows, swizzled transpose-scatter
            int row = lr + 32 * p;
            float4 v = *(const float4*)(Wo + (size_t)(s0 + row) * T4096 + k0 + lk);
            int col = row ^ sw;
            Bs[lk + 0][col] = v.x; Bs[lk + 1][col] = v.y;
            Bs[lk + 2][col] = v.z; Bs[lk + 3][col] = v.w;
        }
        __syncthreads();
#pragma unroll
        for (int k = 0; k < 32; ++k) {
            const int swk = k & 28;
            float4 a  = *(const float4*)&As[k][c0];
            float4 b0 = *(const float4*)&Bs[k][(sl) ^ swk];
            float4 b1 = *(const float4*)&Bs[k][(sl + 4) ^ swk];
            float av[4] = {a.x, a.y, a.z, a.w};
            float bv[8] = {b0.x,b0.y,b0.z,b0.w,b1.x,b1.y,b1.z,b1.w};
#pragma unroll
            for (int i = 0; i < 4; ++i)
#pragma unroll
                for (int j = 0; j < 8; ++j) acc[i][j] = fmaf(av[i], bv[j], acc[i][j]);
        }
        __syncthreads();
    }
#pragma unroll
    for (int i = 0; i < 4; ++i) {
        float* dst = Out + ((size_t)b * CH + c0 + i) * T4096 + s0 + sl;
        *(float4*)dst       = make_float4(acc[i][0], acc[i][1], acc[i][2], acc[i][3]);
        *(float4*)(dst + 4) = make_float4(acc[i][4], acc[i][5], acc[i][6], acc[i][7]);
    }
}

// ---------------------------------------------------------------------------
extern "C" void kernel_launch(void* const* d_in, const int* in_sizes, int n_in,
                              void* d_out, int out_size, void* d_ws, size_t ws_size,
                              hipStream_t stream)
{
    const float* x  = (const float*)d_in[0];
    const float* Wq = (const float*)d_in[1];
    const float* Wk = (const float*)d_in[2];
    const float* Wv = (const float*)d_in[3];
    const float* Wo = (const float*)d_in[4];
    const float* cw = (const float*)d_in[5];
    const float* cb = (const float*)d_in[6];
    float* Out = (float*)d_out;

    char* ws = (char*)d_ws;
    float* QT   = (float*)(ws);                               // 8 MB  Q tiled [b][blk][c4g][sl][4]
    float* KT   = (float*)(ws + (size_t)8  * 1024 * 1024);    // 8 MB  [b][s][c]
    float* VT   = (float*)(ws + (size_t)16 * 1024 * 1024);    // 8 MB  [b][s][c]
    int*   IDXb = (int*)  (ws + (size_t)24 * 1024 * 1024);    // 1.2 MB [b][t][9]
    float* wT3  = (float*)(ws + (size_t)26 * 1024 * 1024);    // 147 KB
    float* out1 = QT;   // QT dead after sim_topk; reuse as conv output [b][t][o]

    gemm_qkv<<<dim3(32, 8, 3), dim3(256), 0, stream>>>(x, Wq, Wk, Wv, QT, KT, VT);
    normalize_qk<<<dim3(16384), dim3(256), 0, stream>>>(QT, KT);
    sim_topk<<<dim3(1024), dim3(512), 0, stream>>>(QT, KT, IDXb);
    transpose_w<<<dim3(144), dim3(256), 0, stream>>>(cw, wT3);
    gather_conv<<<dim3(256, 8), dim3(256), 0, stream>>>(VT, IDXb, wT3, cb, out1);
    gemm_out<<<dim3(32, 8), dim3(256), 0, stream>>>(out1, Wo, Out);
}

// Round 10
// 1617.672 us; speedup vs baseline: 1.0762x; 1.0762x over previous
//
#include <hip/hip_runtime.h>

#define T4096 4096
#define CH 64
typedef unsigned long long u64;

// ---------------------------------------------------------------------------
// QKV: O[b][s][c] = sum_t W[s][t] * X[b][c][t]   (NT gemm, both row-major in t)
// tile 128(s) x 64(c), K-step 64, **512 threads**, 4x4 micro-tile.
// 8 waves/block x 3 blocks/CU (51.2 KB LDS) = 24 waves/CU (75% occ) for
// barrier-latency hiding. LDS [k][col^swz], col = row ^ (k & 28) (0 confl).
// Q stored TILED: Qr2[b][blk=s/64][c4g][sl=s%64][4].
// Per-output fmaf chain k-ascending over identical values -> bit-identical.
// ---------------------------------------------------------------------------
__global__ __launch_bounds__(512) void gemm_qkv(
    const float* __restrict__ X,
    const float* __restrict__ Wq, const float* __restrict__ Wk, const float* __restrict__ Wv,
    float* __restrict__ QT, float* __restrict__ KT, float* __restrict__ VT)
{
    const float* W = (blockIdx.z == 0) ? Wq : (blockIdx.z == 1) ? Wk : Wv;
    float*       O = (blockIdx.z == 0) ? QT : (blockIdx.z == 1) ? KT : VT;
    const int b  = blockIdx.y;
    const int s0 = blockIdx.x * 128;

    __shared__ float As[64][132];   // [k][m^swz]
    __shared__ float Bs[64][68];    // [k][c^swz]

    const int tid = threadIdx.x;
    const int tx = tid & 15;   const int c0 = tx * 4;
    const int my = tid >> 4;   const int m0 = my * 4;   // 0..124
    const int lr = tid >> 3;            // 0..63
    const int lk = (tid & 7) * 4;       // 0..28
    const int sw = lk;

    float acc[4][4];
#pragma unroll
    for (int i = 0; i < 4; ++i)
#pragma unroll
        for (int j = 0; j < 4; ++j) acc[i][j] = 0.f;

    const float* Xb = X + (size_t)b * CH * T4096;

    for (int k0 = 0; k0 < T4096; k0 += 64) {
#pragma unroll
        for (int kk = 0; kk < 2; ++kk) {
            const int kb = 32 * kk + lk;
#pragma unroll
            for (int p = 0; p < 2; ++p) {   // A: 128 rows
                int row = lr + 64 * p;
                float4 v = *(const float4*)(W + (size_t)(s0 + row) * T4096 + k0 + kb);
                int col = row ^ sw;
                As[kb + 0][col] = v.x; As[kb + 1][col] = v.y;
                As[kb + 2][col] = v.z; As[kb + 3][col] = v.w;
            }
            {   // B: 64 rows (channels)
                int row = lr;
                float4 v = *(const float4*)(Xb + (size_t)row * T4096 + k0 + kb);
                int col = row ^ sw;
                Bs[kb + 0][col] = v.x; Bs[kb + 1][col] = v.y;
                Bs[kb + 2][col] = v.z; Bs[kb + 3][col] = v.w;
            }
        }
        __syncthreads();
#pragma unroll
        for (int k = 0; k < 64; ++k) {
            const int swk = k & 28;
            float4 a  = *(const float4*)&As[k][m0 ^ swk];
            float4 bv = *(const float4*)&Bs[k][c0 ^ swk];
            float am[4] = {a.x, a.y, a.z, a.w};
            float bn[4] = {bv.x, bv.y, bv.z, bv.w};
#pragma unroll
            for (int i = 0; i < 4; ++i)
#pragma unroll
                for (int j = 0; j < 4; ++j) acc[i][j] = fmaf(am[i], bn[j], acc[i][j]);
        }
        __syncthreads();
    }
    if (blockIdx.z == 0) {
        // tiled store: Qr2[b][blk][c4g=tx][sl][4]
#pragma unroll
        for (int i = 0; i < 4; ++i) {
            int s = s0 + m0 + i;
            *(float4*)(O + ((((size_t)b * 64 + (s >> 6)) * 16 + tx) * 64 + (s & 63)) * 4) =
                make_float4(acc[i][0], acc[i][1], acc[i][2], acc[i][3]);
        }
    } else {
#pragma unroll
        for (int i = 0; i < 4; ++i) {
            *(float4*)(O + ((size_t)b * T4096 + s0 + m0 + i) * CH + c0) =
                make_float4(acc[i][0], acc[i][1], acc[i][2], acc[i][3]);
        }
    }
}

// ---------------------------------------------------------------------------
// In-place L2 normalize over the 64 channels of each token (Q then K).
// One wave per token. Q uses the tiled layout; lane<->channel mapping and
// the butterfly order are unchanged -> bit-exact.
// ---------------------------------------------------------------------------
__global__ __launch_bounds__(256) void normalize_qk(float* __restrict__ QT, float* __restrict__ KT)
{
    int gtok = blockIdx.x * 4 + (threadIdx.x >> 6);
    int lane = threadIdx.x & 63;
    bool isQ = (gtok < 8 * T4096);
    int t = gtok & (T4096 - 1);
    int b = (gtok >> 12) & 7;
    float* p;
    if (isQ) p = QT + ((((size_t)b * 64 + (t >> 6)) * 16 + (lane >> 2)) * 64 + (t & 63)) * 4 + (lane & 3);
    else     p = KT + ((size_t)b * T4096 + t) * CH + lane;
    float v = *p;
    float ss = v * v;
#pragma unroll
    for (int off = 32; off; off >>= 1) ss += __shfl_xor(ss, off);
    float n = fmaxf(sqrtf(ss), 1e-12f);
    *p = v / n;
}

// ---------------------------------------------------------------------------
// Fused sim + top-9, v8 (unchanged from R9): 2 rows x 8 cols per thread,
// 256-col chunks. u64 keys + 32-bit pre-guard + row-shared threshold.
// IDX bit-identical to all prior rounds.
// ---------------------------------------------------------------------------
__global__ __launch_bounds__(512) void sim_topk(
    const float* __restrict__ Qr, const float* __restrict__ KT, int* __restrict__ IDX)
{
    const int wg = blockIdx.x;
    const int b  = wg & 7;              // XCD affinity
    const int t0 = (wg >> 3) * 32;

    __shared__ float Kn[32][68];

    const int tid = threadIdx.x;
    const int tx = tid & 31;
    const int ty = tid >> 5;            // 0..15

    {   // stage 32 rows x 64 floats, 4 floats/thread (one-time)
        int row = tid >> 4; int cc = (tid & 15) * 4;
        *(float4*)&Kn[row][cc] =
            *(const float4*)(KT + ((size_t)b * T4096 + t0 + row) * CH + cc);
    }
    __syncthreads();

    u64 tv[2][9];
#pragma unroll
    for (int r = 0; r < 2; ++r)
#pragma unroll
        for (int q = 0; q < 9; ++q) tv[r][q] = 0ULL;
    u64 thr[2] = {0ULL, 0ULL};
    unsigned thr_hi[2] = {0u, 0u};

    const float* qb0 = Qr + ((size_t)b * 64 * 1024 + tx) * 4;

    for (int it = 0; it < 16; ++it) {
        const float* bp = qb0 + (size_t)(it * 4) * 4096;
        float acc[2][8];
#pragma unroll
        for (int c = 0; c < 8; ++c) { acc[0][c] = 0.f; acc[1][c] = 0.f; }

#pragma unroll 1
        for (int c4g = 0; c4g < 16; ++c4g) {
            float4 qv[8];
#pragma unroll
            for (int cc = 0; cc < 8; ++cc)
                qv[cc] = *(const float4*)(bp + (size_t)(cc >> 1) * 4096
                                             + c4g * 256 + (cc & 1) * 128);
            float4 k0 = *(const float4*)&Kn[ty][c4g * 4];
            float4 k1 = *(const float4*)&Kn[16 + ty][c4g * 4];
#pragma unroll
            for (int cc = 0; cc < 8; ++cc) {
                acc[0][cc] = fmaf(k0.x, qv[cc].x, acc[0][cc]);
                acc[0][cc] = fmaf(k0.y, qv[cc].y, acc[0][cc]);
                acc[0][cc] = fmaf(k0.z, qv[cc].z, acc[0][cc]);
                acc[0][cc] = fmaf(k0.w, qv[cc].w, acc[0][cc]);
                acc[1][cc] = fmaf(k1.x, qv[cc].x, acc[1][cc]);
                acc[1][cc] = fmaf(k1.y, qv[cc].y, acc[1][cc]);
                acc[1][cc] = fmaf(k1.z, qv[cc].z, acc[1][cc]);
                acc[1][cc] = fmaf(k1.w, qv[cc].w, acc[1][cc]);
            }
        }

        bool ins = false;
        const int sb = it * 256 + tx;
#pragma unroll
        for (int rr = 0; rr < 2; ++rr)
#pragma unroll
            for (int cc = 0; cc < 8; ++cc) {
                float v = fmaxf(acc[rr][cc], 0.f);     // clip BEFORE top-k (as ref)
                unsigned vb = __float_as_uint(v);
                if (vb >= thr_hi[rr]) {                // cheap 32-bit pre-guard
                    int s = sb + 32 * cc;
                    u64 key = ((u64)vb << 32) | (u64)(4095 - s);
                    if (key > thr[rr]) {               // exact guard
                        u64 cv = key;
#pragma unroll
                        for (int p = 0; p < 9; ++p) {  // branchless sorted insert
                            u64 t  = tv[rr][p];
                            bool g = cv > t;
                            tv[rr][p] = g ? cv : t;
                            cv        = g ? t  : cv;
                        }
                        ins = true;
                    }
                }
            }
        if (__any(ins)) {   // refresh row lower bounds (max of lane 9ths)
#pragma unroll
            for (int r = 0; r < 2; ++r) {
                u64 m = tv[r][8];
#pragma unroll
                for (int msk = 1; msk < 32; msk <<= 1) {
                    u64 o = __shfl_xor(m, msk);
                    if (o > m) m = o;
                }
                thr[r] = m;
                thr_hi[r] = (unsigned)(m >> 32);
            }
        }
    }

    // in-wave merge: 32 lanes sharing ty hold sorted 9-lists for row rr*16+ty.
#pragma unroll
    for (int rr = 0; rr < 2; ++rr) {
        u64 mv[9];
#pragma unroll
        for (int q = 0; q < 9; ++q) mv[q] = tv[rr][q];
        const int outrow = t0 + rr * 16 + ty;
        int* dst = IDX + ((size_t)b * T4096 + outrow) * 9;
        for (int sel = 0; sel < 9; ++sel) {
            u64 bk = mv[0]; int bl = tx;
#pragma unroll
            for (int m = 1; m < 32; m <<= 1) {
                u64 ok = __shfl_xor(bk, m);
                int ol = __shfl_xor(bl, m);
                if (ok > bk) { bk = ok; bl = ol; }
            }
            if (tx == 0) dst[sel] = 4095 - (int)(unsigned)bk;
            if (tx == bl) {   // consume winner: static shift
#pragma unroll
                for (int q = 0; q < 8; ++q) mv[q] = mv[q + 1];
                mv[8] = 0ULL;
            }
        }
    }
}

// ---------------------------------------------------------------------------
// conv_w [o][i][j] -> wT3 [j][i/4][o][4] for coalesced float4 lane loads
// ---------------------------------------------------------------------------
__global__ void transpose_w(const float* __restrict__ cw, float* __restrict__ wT3)
{
    int idx = blockIdx.x * 256 + threadIdx.x;
    if (idx >= 64 * 64 * 9) return;
    int q   = idx & 3;
    int o   = (idx >> 2) & 63;
    int i4g = (idx >> 8) & 15;
    int j   = idx >> 12;
    wT3[idx] = cw[o * 576 + (i4g * 4 + q) * 9 + j];
}

// ---------------------------------------------------------------------------
// gather + conv1d(K=9, stride 9) + bias. Wave = 4 tokens x 64 o-lanes.
// out1 layout [b][t][o] (coalesced write, transpose-free LDS load in gemm_out)
// ---------------------------------------------------------------------------
__global__ __launch_bounds__(256) void gather_conv(
    const float* __restrict__ VT, const int* __restrict__ IDX,
    const float* __restrict__ wT3, const float* __restrict__ conv_b,
    float* __restrict__ out1)
{
    const int b  = blockIdx.y;
    const int w  = threadIdx.x >> 6;
    const int o  = threadIdx.x & 63;
    const int t0 = (blockIdx.x * 4 + w) * 4;

    __shared__ float vv[4][4][9][64];
    __shared__ int   nb[4][36];

    if (o < 36) nb[w][o] = IDX[((size_t)b * T4096 + t0) * 9 + o];
    __syncthreads();

#pragma unroll
    for (int tok = 0; tok < 4; ++tok)
#pragma unroll
        for (int j = 0; j < 9; ++j) {
            int n = nb[w][tok * 9 + j];
            vv[w][tok][j][o] = VT[((size_t)b * T4096 + n) * CH + o];
        }
    __syncthreads();

    float cb = conv_b[o];
    float a0 = cb, a1 = cb, a2 = cb, a3 = cb;
    for (int j = 0; j < 9; ++j) {
#pragma unroll
        for (int i4 = 0; i4 < 16; ++i4) {
            float4 w4 = *(const float4*)(wT3 + (((size_t)j * 16 + i4) * 64 + o) * 4);
            float4 v0 = *(const float4*)&vv[w][0][j][i4 * 4];
            float4 v1 = *(const float4*)&vv[w][1][j][i4 * 4];
            float4 v2 = *(const float4*)&vv[w][2][j][i4 * 4];
            float4 v3 = *(const float4*)&vv[w][3][j][i4 * 4];
            a0 = fmaf(v0.x, w4.x, a0); a0 = fmaf(v0.y, w4.y, a0); a0 = fmaf(v0.z, w4.z, a0); a0 = fmaf(v0.w, w4.w, a0);
            a1 = fmaf(v1.x, w4.x, a1); a1 = fmaf(v1.y, w4.y, a1); a1 = fmaf(v1.z, w4.z, a1); a1 = fmaf(v1.w, w4.w, a1);
            a2 = fmaf(v2.x, w4.x, a2); a2 = fmaf(v2.y, w4.y, a2); a2 = fmaf(v2.z, w4.z, a2); a2 = fmaf(v2.w, w4.w, a2);
            a3 = fmaf(v3.x, w4.x, a3); a3 = fmaf(v3.y, w4.y, a3); a3 = fmaf(v3.z, w4.z, a3); a3 = fmaf(v3.w, w4.w, a3);
        }
    }
    out1[((size_t)b * T4096 + t0 + 0) * CH + o] = a0;
    out1[((size_t)b * T4096 + t0 + 1) * CH + o] = a1;
    out1[((size_t)b * T4096 + t0 + 2) * CH + o] = a2;
    out1[((size_t)b * T4096 + t0 + 3) * CH + o] = a3;
}

// ---------------------------------------------------------------------------
// Final: Out[b][c][s] = sum_t out1[b][t][c] * Wo[s][t]
// tile 64(c) x 64(s), K-step 64, 256 thr, 4x4 micro-tile.
// Grid 512 blocks (2/CU) vs prior 256 (1/CU, 12.5% occ) — occupancy fix.
// Per-output fmaf chain k-ascending over identical values -> bit-identical.
// ---------------------------------------------------------------------------
__global__ __launch_bounds__(256) void gemm_out(
    const float* __restrict__ out1, const float* __restrict__ Wo, float* __restrict__ Out)
{
    const int b  = blockIdx.y;
    const int s0 = blockIdx.x * 64;
    __shared__ float As[64][68];    // [k][c]
    __shared__ float Bs[64][68];    // [k][s^swz]
    const int tid = threadIdx.x;
    const int tx = tid & 15;  const int sl = tx * 4;
    const int my = tid >> 4;  const int c0 = my * 4;
    const int lk = (tid & 7) * 4;
    const int sw = lk;

    float acc[4][4];
#pragma unroll
    for (int i = 0; i < 4; ++i)
#pragma unroll
        for (int j = 0; j < 4; ++j) acc[i][j] = 0.f;

    for (int k0 = 0; k0 < T4096; k0 += 64) {
        {   // A: out1 is [t][c] -> direct [k][c] copy, no transpose
            int r  = tid >> 2;              // 0..63
            int cL = (tid & 3) * 16;
            const float* src = out1 + ((size_t)b * T4096 + k0 + r) * CH + cL;
#pragma unroll
            for (int q = 0; q < 4; ++q)
                *(float4*)&As[r][cL + 4 * q] = *(const float4*)(src + 4 * q);
        }
#pragma unroll
        for (int kk = 0; kk < 2; ++kk) {    // B: Wo rows, swizzled scatter
            const int kb = 32 * kk + lk;
#pragma unroll
            for (int p = 0; p < 2; ++p) {
                int row = (tid >> 3) + 32 * p;   // 0..63 (s within tile)
                float4 v = *(const float4*)(Wo + (size_t)(s0 + row) * T4096 + k0 + kb);
                int col = row ^ sw;
                Bs[kb + 0][col] = v.x; Bs[kb + 1][col] = v.y;
                Bs[kb + 2][col] = v.z; Bs[kb + 3][col] = v.w;
            }
        }
        __syncthreads();
#pragma unroll
        for (int k = 0; k < 64; ++k) {
            const int swk = k & 28;
            float4 a  = *(const float4*)&As[k][c0];
            float4 bv = *(const float4*)&Bs[k][sl ^ swk];
            float av[4] = {a.x, a.y, a.z, a.w};
            float bn[4] = {bv.x, bv.y, bv.z, bv.w};
#pragma unroll
            for (int i = 0; i < 4; ++i)
#pragma unroll
                for (int j = 0; j < 4; ++j) acc[i][j] = fmaf(av[i], bn[j], acc[i][j]);
        }
        __syncthreads();
    }
#pragma unroll
    for (int i = 0; i < 4; ++i) {
        float* dst = Out + ((size_t)b * CH + c0 + i) * T4096 + s0 + sl;
        *(float4*)dst = make_float4(acc[i][0], acc[i][1], acc[i][2], acc[i][3]);
    }
}

// ---------------------------------------------------------------------------
extern "C" void kernel_launch(void* const* d_in, const int* in_sizes, int n_in,
                              void* d_out, int out_size, void* d_ws, size_t ws_size,
                              hipStream_t stream)
{
    const float* x  = (const float*)d_in[0];
    const float* Wq = (const float*)d_in[1];
    const float* Wk = (const float*)d_in[2];
    const float* Wv = (const float*)d_in[3];
    const float* Wo = (const float*)d_in[4];
    const float* cw = (const float*)d_in[5];
    const float* cb = (const float*)d_in[6];
    float* Out = (float*)d_out;

    char* ws = (char*)d_ws;
    float* QT   = (float*)(ws);                               // 8 MB  Q tiled [b][blk][c4g][sl][4]
    float* KT   = (float*)(ws + (size_t)8  * 1024 * 1024);    // 8 MB  [b][s][c]
    float* VT   = (float*)(ws + (size_t)16 * 1024 * 1024);    // 8 MB  [b][s][c]
    int*   IDXb = (int*)  (ws + (size_t)24 * 1024 * 1024);    // 1.2 MB [b][t][9]
    float* wT3  = (float*)(ws + (size_t)26 * 1024 * 1024);    // 147 KB
    float* out1 = QT;   // QT dead after sim_topk; reuse as conv output [b][t][o]

    gemm_qkv<<<dim3(32, 8, 3), dim3(512), 0, stream>>>(x, Wq, Wk, Wv, QT, KT, VT);
    normalize_qk<<<dim3(16384), dim3(256), 0, stream>>>(QT, KT);
    sim_topk<<<dim3(1024), dim3(512), 0, stream>>>(QT, KT, IDXb);
    transpose_w<<<dim3(144), dim3(256), 0, stream>>>(cw, wT3);
    gather_conv<<<dim3(256, 8), dim3(256), 0, stream>>>(VT, IDXb, wT3, cb, out1);
    gemm_out<<<dim3(64, 8), dim3(256), 0, stream>>>(out1, Wo, Out);
}